// Round 3
// baseline (116.402 us; speedup 1.0000x reference)
//
#include <hip/hip_runtime.h>

typedef unsigned short u16;
typedef __attribute__((ext_vector_type(4))) float f32x4;
typedef __attribute__((ext_vector_type(8))) short bf16x8;
typedef __attribute__((ext_vector_type(4))) u16 u16x4;

#define MFMA(a, b, c) __builtin_amdgcn_mfma_f32_16x16x32_bf16(a, b, c, 0, 0, 0)

__device__ __forceinline__ u16 f2bf(float f) {
    unsigned u = __float_as_uint(f);
    u += 0x7fffu + ((u >> 16) & 1u);   // round-to-nearest-even
    return (u16)(u >> 16);
}

// ---------------------------------------------------------------------------
// Kernel 1: transpose-pack Wq|Wk|Wv (fp32 [1024][64]) -> Wt bf16 [192][1024].
// LDS tile transpose: coalesced reads AND writes. grid (16 kk-tiles, 3 mats).
// ---------------------------------------------------------------------------
__global__ __launch_bounds__(256) void wt_pack(const float* __restrict__ Wq,
                                               const float* __restrict__ Wk,
                                               const float* __restrict__ Wv,
                                               u16* __restrict__ Wt) {
    const int kk0 = blockIdx.x * 64;
    const int n0 = blockIdx.y * 64;
    const float* W = (blockIdx.y == 0) ? Wq : (blockIdx.y == 1 ? Wk : Wv);

    __shared__ float t[64][65];
    const int h = threadIdx.x & 63, r = threadIdx.x >> 6;
#pragma unroll
    for (int i = 0; i < 16; ++i) {
        const int kk = r + i * 4;
        t[kk][h] = W[(size_t)(kk0 + kk) * 64 + h];
    }
    __syncthreads();
    const int kl = threadIdx.x & 63;
#pragma unroll
    for (int i = 0; i < 16; ++i) {
        const int nl = r + i * 4;
        Wt[(size_t)(n0 + nl) * 1024 + kk0 + kl] = f2bf(t[kl][nl]);
    }
}

// ---------------------------------------------------------------------------
// Kernel 2: qkv projection. x fp32 [16384][1024] @ Wt^T -> q,k bf16 [16384][64],
// vT bf16 [8][64][2048]. Zero LDS / zero barriers. BM=32, 4 waves (2Mx2N),
// wave = 16 rows x 96 cols. ALL loads per k-step batched into register arrays
// before the MFMAs (breaks the serial load chain that killed R2).
// ---------------------------------------------------------------------------
__global__ __launch_bounds__(256, 2) void qkv_gemm(const float* __restrict__ x,
                                                   const u16* __restrict__ Wt,
                                                   u16* __restrict__ qo,
                                                   u16* __restrict__ ko,
                                                   u16* __restrict__ vT) {
    const int lane = threadIdx.x & 63, wave = threadIdx.x >> 6;
    const int wr = wave >> 1, wc = wave & 1;
    const int lr = lane & 15, lg = lane >> 4;
    const int m0 = blockIdx.x * 32;

    f32x4 acc[6];
#pragma unroll
    for (int n = 0; n < 6; ++n) acc[n] = (f32x4){0.f, 0.f, 0.f, 0.f};

    const float* xw = x + (size_t)(m0 + wr * 16 + lr) * 1024 + lg * 8;
    const u16* wtb = Wt + (size_t)(wc * 96 + lr) * 1024 + lg * 8;

#pragma unroll 2
    for (int k0 = 0; k0 < 1024; k0 += 64) {
        // ---- batched independent loads (4 x-vecs + 12 B-frags), one wait
        f32x4 xf0 = *(const f32x4*)(xw + k0);
        f32x4 xf1 = *(const f32x4*)(xw + k0 + 4);
        f32x4 xf2 = *(const f32x4*)(xw + k0 + 32);
        f32x4 xf3 = *(const f32x4*)(xw + k0 + 36);
        bf16x8 b[12];
#pragma unroll
        for (int n = 0; n < 6; ++n) {
            b[n] = *(const bf16x8*)(wtb + (size_t)n * 16384 + k0);
            b[6 + n] = *(const bf16x8*)(wtb + (size_t)n * 16384 + k0 + 32);
        }
        bf16x8 a0, a1;
#pragma unroll
        for (int i = 0; i < 4; ++i) {
            a0[i] = (short)f2bf(xf0[i]);
            a0[i + 4] = (short)f2bf(xf1[i]);
            a1[i] = (short)f2bf(xf2[i]);
            a1[i + 4] = (short)f2bf(xf3[i]);
        }
#pragma unroll
        for (int n = 0; n < 6; ++n) acc[n] = MFMA(a0, b[n], acc[n]);
#pragma unroll
        for (int n = 0; n < 6; ++n) acc[n] = MFMA(a1, b[6 + n], acc[n]);
    }

    const int bb = m0 >> 11;          // batch
    const int tb = m0 & 2047;         // t base within batch
#pragma unroll
    for (int n = 0; n < 6; ++n) {
        const int col = wc * 96 + n * 16 + lr;
        const int rl = wr * 16 + lg * 4;
        if (col < 64) {
#pragma unroll
            for (int r = 0; r < 4; ++r)
                qo[(size_t)(m0 + rl + r) * 64 + col] = f2bf(acc[n][r]);
        } else if (col < 128) {
#pragma unroll
            for (int r = 0; r < 4; ++r)
                ko[(size_t)(m0 + rl + r) * 64 + (col - 64)] = f2bf(acc[n][r]);
        } else {
            u16x4 pk;
#pragma unroll
            for (int r = 0; r < 4; ++r) pk[r] = f2bf(acc[n][r]);
            *(u16x4*)&vT[(size_t)(bb * 64 + (col - 128)) * 2048 + tb + rl] = pk;
        }
    }
}

// ---------------------------------------------------------------------------
// Kernel 3: split-KV causal flash attention, barrier-free. Wave = (b, 16 q-rows,
// 512-wide kv chunk). K/V direct from global/L2. Batched K-frag loads before
// QK^T; V-frag loads issued before softmax so they drain under the VALU work.
// ---------------------------------------------------------------------------
__global__ __launch_bounds__(256, 3) void attn_part(const u16* __restrict__ q,
                                                    const u16* __restrict__ k,
                                                    const u16* __restrict__ vT,
                                                    float* __restrict__ Op,
                                                    float* __restrict__ Mp,
                                                    float* __restrict__ Lp) {
    const int b = blockIdx.x & 7;
    const int qt = 127 - (blockIdx.x >> 3);   // heavy-first
    const int wave = threadIdx.x >> 6, lane = threadIdx.x & 63;
    const int c = wave;                       // kv chunk id
    const int q0 = qt * 16;
    const int kv_lo = c * 512;
    const int kv_hi = min(kv_lo + 512, q0 + 16);
    if (kv_lo >= kv_hi) return;               // empty unit (wave-uniform)

    __shared__ __align__(16) u16 lP[4][16 * 72];   // per-wave P [16][72]

    const int lr = lane & 15, lg = lane >> 4;
    const u16* qb = q + (size_t)b * 2048 * 64;
    const u16* kb = k + (size_t)b * 2048 * 64;
    const u16* vb = vT + (size_t)b * 64 * 2048;

    const int qrow = q0 + lr;
    const bf16x8 qf0 = *(const bf16x8*)(qb + (size_t)qrow * 64 + lg * 8);
    const bf16x8 qf1 = *(const bf16x8*)(qb + (size_t)qrow * 64 + 32 + lg * 8);

    f32x4 oacc[4];
#pragma unroll
    for (int n = 0; n < 4; ++n) oacc[n] = (f32x4){0.f, 0.f, 0.f, 0.f};
    float mx[4] = {-3e38f, -3e38f, -3e38f, -3e38f};
    float ls[4] = {0.f, 0.f, 0.f, 0.f};

    const float SC = 1.4426950408889634f / 32.0f;  // log2(e)/sqrt(1024)
    const int row0 = q0 + lg * 4;                  // lane's first S row

    for (int kv0 = kv_lo; kv0 < kv_hi; kv0 += 64) {
        // ---- batched K-frag loads (8 x 16B, independent)
        bf16x8 kf[4][2];
#pragma unroll
        for (int n = 0; n < 4; ++n) {
            const u16* kp = kb + (size_t)(kv0 + n * 16 + lr) * 64 + lg * 8;
            kf[n][0] = *(const bf16x8*)(kp);
            kf[n][1] = *(const bf16x8*)(kp + 32);
        }
        // ---- S = Q K^T
        f32x4 s[4];
#pragma unroll
        for (int n = 0; n < 4; ++n) {
            f32x4 a = (f32x4){0.f, 0.f, 0.f, 0.f};
            a = MFMA(qf0, kf[n][0], a);
            a = MFMA(qf1, kf[n][1], a);
            s[n] = a;
        }
        // ---- issue V loads now; they complete under the softmax VALU work
        bf16x8 vf[2][4];
#pragma unroll
        for (int kc = 0; kc < 2; ++kc)
#pragma unroll
            for (int n = 0; n < 4; ++n)
                vf[kc][n] = *(const bf16x8*)(vb + (size_t)(n * 16 + lr) * 2048 + kv0 +
                                             kc * 32 + lg * 8);

        // ---- scale + causal mask + row max
        float pmax[4] = {-3e38f, -3e38f, -3e38f, -3e38f};
        const bool mask = (kv0 + 63 > q0);
#pragma unroll
        for (int n = 0; n < 4; ++n) {
            const int col = kv0 + n * 16 + lr;
#pragma unroll
            for (int r = 0; r < 4; ++r) {
                float v = s[n][r] * SC;
                if (mask && col > row0 + r) v = -3e38f;
                s[n][r] = v;
                pmax[r] = fmaxf(pmax[r], v);
            }
        }
#pragma unroll
        for (int d = 1; d < 16; d <<= 1)
#pragma unroll
            for (int r = 0; r < 4; ++r) pmax[r] = fmaxf(pmax[r], __shfl_xor(pmax[r], d));

        // ---- online softmax update
        float rowsum[4];
#pragma unroll
        for (int r = 0; r < 4; ++r) {
            const float mn = fmaxf(mx[r], pmax[r]);
            const float sc = exp2f(mx[r] - mn);
            mx[r] = mn;
            ls[r] *= sc;
#pragma unroll
            for (int n = 0; n < 4; ++n) oacc[n][r] *= sc;
            rowsum[r] = 0.f;
        }
#pragma unroll
        for (int n = 0; n < 4; ++n)
#pragma unroll
            for (int r = 0; r < 4; ++r) {
                const float p = exp2f(s[n][r] - mx[r]);
                rowsum[r] += p;
                lP[wave][(lg * 4 + r) * 72 + n * 16 + lr] = f2bf(p);
            }
#pragma unroll
        for (int d = 1; d < 16; d <<= 1)
#pragma unroll
            for (int r = 0; r < 4; ++r) rowsum[r] += __shfl_xor(rowsum[r], d);
#pragma unroll
        for (int r = 0; r < 4; ++r) ls[r] += rowsum[r];

        // ---- PV
#pragma unroll
        for (int kc = 0; kc < 2; ++kc) {
            const bf16x8 pf = *(const bf16x8*)&lP[wave][lr * 72 + kc * 32 + lg * 8];
#pragma unroll
            for (int n = 0; n < 4; ++n) oacc[n] = MFMA(pf, vf[kc][n], oacc[n]);
        }
    }

    // ---- write partials (unnormalized)
    const int slot = ((b << 7) + qt) * 4 + c;
    float* op = Op + (size_t)slot * 1024;
#pragma unroll
    for (int r = 0; r < 4; ++r) {
#pragma unroll
        for (int n = 0; n < 4; ++n) op[(lg * 4 + r) * 64 + n * 16 + lr] = oacc[n][r];
        if (lr == 0) {
            Mp[slot * 16 + lg * 4 + r] = mx[r];
            Lp[slot * 16 + lg * 4 + r] = ls[r];
        }
    }
}

// ---------------------------------------------------------------------------
// Kernel 4: merge <=4 kv-chunk partials per q-row, normalize, write out fp32.
// ---------------------------------------------------------------------------
__global__ __launch_bounds__(256) void attn_combine(const float* __restrict__ Op,
                                                    const float* __restrict__ Mp,
                                                    const float* __restrict__ Lp,
                                                    float* __restrict__ out) {
    const int gid = blockIdx.x * 256 + threadIdx.x;   // 1048576
    const int col = gid & 63;
    const int row = gid >> 6;            // b*2048 + t
    const int b = row >> 11, t = row & 2047;
    const int qt = t >> 4, i = t & 15;
    const int nc = (qt >> 5) + 1;
    const int base = ((b << 7) + qt) * 4;

    float M = -3e38f;
    for (int c = 0; c < nc; ++c) M = fmaxf(M, Mp[(base + c) * 16 + i]);
    float O = 0.f, L = 0.f;
    for (int c = 0; c < nc; ++c) {
        const float w = exp2f(Mp[(base + c) * 16 + i] - M);
        O += w * Op[(size_t)(base + c) * 1024 + i * 64 + col];
        L += w * Lp[(base + c) * 16 + i];
    }
    out[(size_t)row * 64 + col] = O / L;
}

// ---------------------------------------------------------------------------
extern "C" void kernel_launch(void* const* d_in, const int* in_sizes, int n_in,
                              void* d_out, int out_size, void* d_ws, size_t ws_size,
                              hipStream_t stream) {
    const float* x = (const float*)d_in[0];
    const float* Wq = (const float*)d_in[1];
    const float* Wk = (const float*)d_in[2];
    const float* Wv = (const float*)d_in[3];
    float* out = (float*)d_out;

    char* ws = (char*)d_ws;
    u16* Wt = (u16*)ws;                                   // 384 KB @ 0
    u16* qb = (u16*)(ws + (512 << 10));                   // 2 MB
    u16* kb = (u16*)(ws + (512 << 10) + (2 << 20));       // 2 MB
    u16* vT = (u16*)(ws + (512 << 10) + (4 << 20));       // 2 MB
    float* Op = (float*)(ws + (8 << 20));                 // 16.8 MB
    float* Mp = (float*)(ws + (25 << 20));                // 256 KB
    float* Lp = (float*)(ws + (25 << 20) + (512 << 10));  // 256 KB

    wt_pack<<<dim3(16, 3), 256, 0, stream>>>(Wq, Wk, Wv, Wt);
    qkv_gemm<<<512, 256, 0, stream>>>(x, Wt, qb, kb, vT);
    attn_part<<<1024, 256, 0, stream>>>(qb, kb, vT, Op, Mp, Lp);
    attn_combine<<<4096, 256, 0, stream>>>(Op, Mp, Lp, out);
}

// Round 4
// 81.487 us; speedup vs baseline: 1.4285x; 1.4285x over previous
//
#include <hip/hip_runtime.h>

typedef unsigned short u16;
typedef __attribute__((ext_vector_type(4))) float f32x4;
typedef __attribute__((ext_vector_type(8))) short bf16x8;
typedef __attribute__((ext_vector_type(4))) u16 u16x4;

#define MFMA(a, b, c) __builtin_amdgcn_mfma_f32_16x16x32_bf16(a, b, c, 0, 0, 0)

__device__ __forceinline__ u16 f2bf(float f) {
    unsigned u = __float_as_uint(f);
    u += 0x7fffu + ((u >> 16) & 1u);   // round-to-nearest-even
    return (u16)(u >> 16);
}

__device__ __forceinline__ void load_lds16(const void* g, void* l) {
    __builtin_amdgcn_global_load_lds((const __attribute__((address_space(1))) void*)g,
                                     (__attribute__((address_space(3))) void*)l,
                                     16, 0, 0);
}

// ---------------------------------------------------------------------------
// Kernel 1: pack Wq|Wk|Wv (fp32 [1024][64]) -> Wtt bf16, tile-major + swizzled:
// Wtt[kt][n][ (c ^ (n&7))*8 + ci ]  (kt=k/64, c=(k%64)/8, ci=k%8), n=0..191.
// Each 24KB tile stages linearly into LDS; the baked XOR swizzle makes the
// B-frag ds_read_b128 2-way conflict-free. grid 1024 x 192 (k-row per block).
// ---------------------------------------------------------------------------
__global__ void wt_pack(const float* __restrict__ Wq, const float* __restrict__ Wk,
                        const float* __restrict__ Wv, u16* __restrict__ Wtt) {
    const int k = blockIdx.x;        // 0..1023
    const int n = threadIdx.x;       // 0..191
    const float* W = (n < 64) ? Wq : (n < 128 ? Wk : Wv);
    const float v = W[(size_t)k * 64 + (n & 63)];
    const int kt = k >> 6, ks = k & 63, c = ks >> 3, ci = ks & 7;
    Wtt[(size_t)kt * 12288 + n * 64 + (((c ^ (n & 7)) << 3) + ci)] = f2bf(v);
}

// ---------------------------------------------------------------------------
// Kernel 2: qkv projection, m97-structure (global_load_lds + 1 barrier/K-step).
// x fp32 [16384][1024] @ Wt^T -> q,k bf16 [16384][64], vT bf16 [8][64][2048].
// BM=32, BK=64, 512 blocks x 256 thr (2 blocks/CU), double-buffered LDS.
// Waves split N: wave w owns n-frags {3w..3w+2}, both m-frags.
// xs staged with inverse-swizzled per-lane global source (LDS dest linear);
// ws staged linearly (swizzle baked into Wtt global layout).
// ---------------------------------------------------------------------------
__global__ __launch_bounds__(256, 2) void qkv_gemm(const float* __restrict__ x,
                                                   const u16* __restrict__ Wtt,
                                                   u16* __restrict__ qo,
                                                   u16* __restrict__ ko,
                                                   u16* __restrict__ vT) {
    const int tid = threadIdx.x;
    const int lane = tid & 63, wave = tid >> 6;
    const int lr = lane & 15, lg = lane >> 4;
    const int m0 = blockIdx.x * 32;

    __shared__ __align__(16) float xs[2][32 * 64];   // 8KB each
    __shared__ __align__(16) u16 ws[2][192 * 64];    // 24KB each

    f32x4 acc[2][3];
#pragma unroll
    for (int m = 0; m < 2; ++m)
#pragma unroll
        for (int n = 0; n < 3; ++n) acc[m][n] = (f32x4){0.f, 0.f, 0.f, 0.f};

    // staging geometry (per thread): xs j=0..1, ws j=0..5; 16B per lane-load
    const int srow = tid >> 4;            // 0..15
    const int schk = tid & 15;            // x 16B-chunk within row

    // ---- prologue: stage kt=0 into buf 0
    {
        const int kt = 0;
#pragma unroll
        for (int j = 0; j < 2; ++j) {
            const int rr = j * 16 + srow;
            const float* src = x + (size_t)(m0 + rr) * 1024 + kt * 64 + ((schk ^ (rr & 7)) << 2);
            load_lds16(src, &xs[0][j * 1024 + wave * 256]);
        }
#pragma unroll
        for (int j = 0; j < 6; ++j) {
            const u16* src = Wtt + (size_t)kt * 12288 + j * 2048 + tid * 8;
            load_lds16(src, &ws[0][j * 2048 + wave * 512]);
        }
    }
    __syncthreads();

    for (int kt = 0; kt < 16; ++kt) {
        const int cur = kt & 1;
        // ---- stage next K-tile into the other buffer (in flight under compute)
        if (kt < 15) {
            const int nxt = cur ^ 1;
#pragma unroll
            for (int j = 0; j < 2; ++j) {
                const int rr = j * 16 + srow;
                const float* src =
                    x + (size_t)(m0 + rr) * 1024 + (kt + 1) * 64 + ((schk ^ (rr & 7)) << 2);
                load_lds16(src, &xs[nxt][j * 1024 + wave * 256]);
            }
#pragma unroll
            for (int j = 0; j < 6; ++j) {
                const u16* src = Wtt + (size_t)(kt + 1) * 12288 + j * 2048 + tid * 8;
                load_lds16(src, &ws[nxt][j * 2048 + wave * 512]);
            }
        }
        // ---- compute current K-tile
#pragma unroll
        for (int h = 0; h < 2; ++h) {
            bf16x8 a[2];
#pragma unroll
            for (int mm = 0; mm < 2; ++mm) {
                const int rr = mm * 16 + lr;
                const int c0 = h * 8 + lg * 2;
                f32x4 f0 = *(const f32x4*)&xs[cur][rr * 64 + ((c0 ^ (rr & 7)) << 2)];
                f32x4 f1 = *(const f32x4*)&xs[cur][rr * 64 + (((c0 + 1) ^ (rr & 7)) << 2)];
                bf16x8 t;
#pragma unroll
                for (int i = 0; i < 4; ++i) {
                    t[i] = (short)f2bf(f0[i]);
                    t[i + 4] = (short)f2bf(f1[i]);
                }
                a[mm] = t;
            }
#pragma unroll
            for (int nl = 0; nl < 3; ++nl) {
                const int row = (wave * 3 + nl) * 16 + lr;
                const int cb = h * 4 + lg;
                const bf16x8 b = *(const bf16x8*)&ws[cur][row * 64 + ((cb ^ (row & 7)) << 3)];
                acc[0][nl] = MFMA(a[0], b, acc[0][nl]);
                acc[1][nl] = MFMA(a[1], b, acc[1][nl]);
            }
        }
        __syncthreads();
    }

    // ---- epilogue
    const int bb = m0 >> 11;          // batch
    const int tb = m0 & 2047;         // t base within batch
#pragma unroll
    for (int mm = 0; mm < 2; ++mm)
#pragma unroll
        for (int nl = 0; nl < 3; ++nl) {
            const int col = (wave * 3 + nl) * 16 + lr;
            const int rl = mm * 16 + lg * 4;
            if (col < 64) {
#pragma unroll
                for (int r = 0; r < 4; ++r)
                    qo[(size_t)(m0 + rl + r) * 64 + col] = f2bf(acc[mm][nl][r]);
            } else if (col < 128) {
#pragma unroll
                for (int r = 0; r < 4; ++r)
                    ko[(size_t)(m0 + rl + r) * 64 + (col - 64)] = f2bf(acc[mm][nl][r]);
            } else {
                u16x4 pk;
#pragma unroll
                for (int r = 0; r < 4; ++r) pk[r] = f2bf(acc[mm][nl][r]);
                *(u16x4*)&vT[(size_t)(bb * 64 + (col - 128)) * 2048 + tb + rl] = pk;
            }
        }
}

// ---------------------------------------------------------------------------
// Kernel 3: split-KV causal flash attention, barrier-free (unchanged from R3).
// ---------------------------------------------------------------------------
__global__ __launch_bounds__(256, 3) void attn_part(const u16* __restrict__ q,
                                                    const u16* __restrict__ k,
                                                    const u16* __restrict__ vT,
                                                    float* __restrict__ Op,
                                                    float* __restrict__ Mp,
                                                    float* __restrict__ Lp) {
    const int b = blockIdx.x & 7;
    const int qt = 127 - (blockIdx.x >> 3);   // heavy-first
    const int wave = threadIdx.x >> 6, lane = threadIdx.x & 63;
    const int c = wave;                       // kv chunk id
    const int q0 = qt * 16;
    const int kv_lo = c * 512;
    const int kv_hi = min(kv_lo + 512, q0 + 16);
    if (kv_lo >= kv_hi) return;               // empty unit (wave-uniform)

    __shared__ __align__(16) u16 lP[4][16 * 72];   // per-wave P [16][72]

    const int lr = lane & 15, lg = lane >> 4;
    const u16* qb = q + (size_t)b * 2048 * 64;
    const u16* kb = k + (size_t)b * 2048 * 64;
    const u16* vb = vT + (size_t)b * 64 * 2048;

    const int qrow = q0 + lr;
    const bf16x8 qf0 = *(const bf16x8*)(qb + (size_t)qrow * 64 + lg * 8);
    const bf16x8 qf1 = *(const bf16x8*)(qb + (size_t)qrow * 64 + 32 + lg * 8);

    f32x4 oacc[4];
#pragma unroll
    for (int n = 0; n < 4; ++n) oacc[n] = (f32x4){0.f, 0.f, 0.f, 0.f};
    float mx[4] = {-3e38f, -3e38f, -3e38f, -3e38f};
    float ls[4] = {0.f, 0.f, 0.f, 0.f};

    const float SC = 1.4426950408889634f / 32.0f;  // log2(e)/sqrt(1024)
    const int row0 = q0 + lg * 4;                  // lane's first S row

    for (int kv0 = kv_lo; kv0 < kv_hi; kv0 += 64) {
        // ---- batched K-frag loads
        bf16x8 kf[4][2];
#pragma unroll
        for (int n = 0; n < 4; ++n) {
            const u16* kp = kb + (size_t)(kv0 + n * 16 + lr) * 64 + lg * 8;
            kf[n][0] = *(const bf16x8*)(kp);
            kf[n][1] = *(const bf16x8*)(kp + 32);
        }
        // ---- S = Q K^T
        f32x4 s[4];
#pragma unroll
        for (int n = 0; n < 4; ++n) {
            f32x4 a = (f32x4){0.f, 0.f, 0.f, 0.f};
            a = MFMA(qf0, kf[n][0], a);
            a = MFMA(qf1, kf[n][1], a);
            s[n] = a;
        }
        // ---- issue V loads now; they complete under the softmax VALU work
        bf16x8 vf[2][4];
#pragma unroll
        for (int kc = 0; kc < 2; ++kc)
#pragma unroll
            for (int n = 0; n < 4; ++n)
                vf[kc][n] = *(const bf16x8*)(vb + (size_t)(n * 16 + lr) * 2048 + kv0 +
                                             kc * 32 + lg * 8);

        // ---- scale + causal mask + row max
        float pmax[4] = {-3e38f, -3e38f, -3e38f, -3e38f};
        const bool mask = (kv0 + 63 > q0);
#pragma unroll
        for (int n = 0; n < 4; ++n) {
            const int col = kv0 + n * 16 + lr;
#pragma unroll
            for (int r = 0; r < 4; ++r) {
                float v = s[n][r] * SC;
                if (mask && col > row0 + r) v = -3e38f;
                s[n][r] = v;
                pmax[r] = fmaxf(pmax[r], v);
            }
        }
#pragma unroll
        for (int d = 1; d < 16; d <<= 1)
#pragma unroll
            for (int r = 0; r < 4; ++r) pmax[r] = fmaxf(pmax[r], __shfl_xor(pmax[r], d));

        // ---- online softmax update
        float rowsum[4];
#pragma unroll
        for (int r = 0; r < 4; ++r) {
            const float mn = fmaxf(mx[r], pmax[r]);
            const float sc = exp2f(mx[r] - mn);
            mx[r] = mn;
            ls[r] *= sc;
#pragma unroll
            for (int n = 0; n < 4; ++n) oacc[n][r] *= sc;
            rowsum[r] = 0.f;
        }
#pragma unroll
        for (int n = 0; n < 4; ++n)
#pragma unroll
            for (int r = 0; r < 4; ++r) {
                const float p = exp2f(s[n][r] - mx[r]);
                rowsum[r] += p;
                lP[wave][(lg * 4 + r) * 72 + n * 16 + lr] = f2bf(p);
            }
#pragma unroll
        for (int d = 1; d < 16; d <<= 1)
#pragma unroll
            for (int r = 0; r < 4; ++r) rowsum[r] += __shfl_xor(rowsum[r], d);
#pragma unroll
        for (int r = 0; r < 4; ++r) ls[r] += rowsum[r];

        // ---- PV
#pragma unroll
        for (int kc = 0; kc < 2; ++kc) {
            const bf16x8 pf = *(const bf16x8*)&lP[wave][lr * 72 + kc * 32 + lg * 8];
#pragma unroll
            for (int n = 0; n < 4; ++n) oacc[n] = MFMA(pf, vf[kc][n], oacc[n]);
        }
    }

    // ---- write partials (unnormalized)
    const int slot = ((b << 7) + qt) * 4 + c;
    float* op = Op + (size_t)slot * 1024;
#pragma unroll
    for (int r = 0; r < 4; ++r) {
#pragma unroll
        for (int n = 0; n < 4; ++n) op[(lg * 4 + r) * 64 + n * 16 + lr] = oacc[n][r];
        if (lr == 0) {
            Mp[slot * 16 + lg * 4 + r] = mx[r];
            Lp[slot * 16 + lg * 4 + r] = ls[r];
        }
    }
}

// ---------------------------------------------------------------------------
// Kernel 4: merge <=4 kv-chunk partials per q-row, normalize, write out fp32.
// ---------------------------------------------------------------------------
__global__ __launch_bounds__(256) void attn_combine(const float* __restrict__ Op,
                                                    const float* __restrict__ Mp,
                                                    const float* __restrict__ Lp,
                                                    float* __restrict__ out) {
    const int gid = blockIdx.x * 256 + threadIdx.x;   // 1048576
    const int col = gid & 63;
    const int row = gid >> 6;            // b*2048 + t
    const int b = row >> 11, t = row & 2047;
    const int qt = t >> 4, i = t & 15;
    const int nc = (qt >> 5) + 1;
    const int base = ((b << 7) + qt) * 4;

    float M = -3e38f;
    for (int c = 0; c < nc; ++c) M = fmaxf(M, Mp[(base + c) * 16 + i]);
    float O = 0.f, L = 0.f;
    for (int c = 0; c < nc; ++c) {
        const float w = exp2f(Mp[(base + c) * 16 + i] - M);
        O += w * Op[(size_t)(base + c) * 1024 + i * 64 + col];
        L += w * Lp[(base + c) * 16 + i];
    }
    out[(size_t)row * 64 + col] = O / L;
}

// ---------------------------------------------------------------------------
extern "C" void kernel_launch(void* const* d_in, const int* in_sizes, int n_in,
                              void* d_out, int out_size, void* d_ws, size_t ws_size,
                              hipStream_t stream) {
    const float* x = (const float*)d_in[0];
    const float* Wq = (const float*)d_in[1];
    const float* Wk = (const float*)d_in[2];
    const float* Wv = (const float*)d_in[3];
    float* out = (float*)d_out;

    char* ws = (char*)d_ws;
    u16* Wtt = (u16*)ws;                                  // 384 KB @ 0
    u16* qb = (u16*)(ws + (512 << 10));                   // 2 MB
    u16* kb = (u16*)(ws + (512 << 10) + (2 << 20));       // 2 MB
    u16* vT = (u16*)(ws + (512 << 10) + (4 << 20));       // 2 MB
    float* Op = (float*)(ws + (8 << 20));                 // 16.8 MB
    float* Mp = (float*)(ws + (25 << 20));                // 256 KB
    float* Lp = (float*)(ws + (25 << 20) + (512 << 10));  // 256 KB

    wt_pack<<<1024, 192, 0, stream>>>(Wq, Wk, Wv, Wtt);
    qkv_gemm<<<512, 256, 0, stream>>>(x, Wtt, qb, kb, vT);
    attn_part<<<1024, 256, 0, stream>>>(qb, kb, vT, Op, Mp, Lp);
    attn_combine<<<4096, 256, 0, stream>>>(Op, Mp, Lp, out);
}